// Round 7
// baseline (286.774 us; speedup 1.0000x reference)
//
#include <hip/hip_runtime.h>
#include <math.h>

#define N_QUBITS 24
#define N_BLOCKS 4
#define NSTATE (1 << N_QUBITS)

// Qubit q <-> flat-index bit (23 - q).
// Per block (by commutation): RY(0); for q=1..23: RY(q); CNOT(q-1,q)
// Ping-pong buffers, alternating layouts (race-free: src != dst).
//   standard: addr = e23..e0
//   pi:       addr = e[6..14]<<15 | H<<6 | e[0..5],  H bit k = e(15+k)
// P1  (qubits 0..8):  d_out std (scattered 256B reads) -> d_ws pi (contiguous)
// P23 (qubits 9..23): d_ws pi (scattered 256B reads) -> d_out std (contiguous)
// P23: 512 thr, 64 regs, LDS 64 KiB (2 wg/CU). Three transposes, each chunked
// into 2 rounds of 16K floats; split bit holds the SAME register/w position on
// both sides of each transpose -> rounds are clobber-free (no temp registers):
//   L0: regs=(e9..e13, e14@bit5), w=e6..8, lane=e0..5      [entry]
//   T1 (split e14=regbit5) -> L1: regs=(e3..e7, e14@bit5), lane=(e9..e13, e8@bit5), w=e0..2
//   T2 (split e14=regbit5) -> L2: regs=(e0..e4, e14@bit5), lane=e5..10, w=(e11,e12,e13)
//   T3 (split e12=w bit1)  -> L3: regs=e6..11, lane=e0..5, w=(e14,e12,e13)
// Qubit 15 (tgt e8) is a shfl_xor(32) lane gate in L1. Each LDS pattern uses a
// hand-built XOR bank map (verified <=2-way, bijective).

// ---- 64-reg gate helpers ----
template <int B>
__device__ __forceinline__ void pair_bit(float (&a)[64], float s, float c, int swap) {
#pragma unroll
    for (int g = 0; g < 32; ++g) {
        int r0 = ((g >> B) << (B + 1)) | (g & ((1 << B) - 1));
        int r1 = r0 | (1 << B);
        float v0 = a[r0], v1 = a[r1];
        float o0 = c * v0 - s * v1;
        float o1 = s * v0 + c * v1;
        a[r0] = swap ? o1 : o0;
        a[r1] = swap ? o0 : o1;
    }
}
// Fused RY(tgt = reg bit BT) then CNOT(ctrl = reg bit BT+1, tgt = reg bit BT).
template <int BT>
__device__ __forceinline__ void quad_gate(float (&a)[64], float s, float c) {
#pragma unroll
    for (int g = 0; g < 16; ++g) {
        int lo  = g & ((1 << BT) - 1);
        int r00 = ((g >> BT) << (BT + 2)) | lo;
        int r01 = r00 | (1 << BT);
        int r10 = r00 | (2 << BT);
        int r11 = r00 | (3 << BT);
        float v00 = a[r00], v01 = a[r01], v10 = a[r10], v11 = a[r11];
        a[r00] = c * v00 - s * v01;
        a[r01] = s * v00 + c * v01;
        a[r10] = s * v10 + c * v11;   // ctrl=1 half: RY then swap (CNOT)
        a[r11] = c * v10 - s * v11;
    }
}

// ---------------- Pass 1 (std -> pi): qubits 0..8 (bits 15..23) ----------------
// Unchanged from R5 (proven ~32 us). 512 thr, 64 KiB LDS, contiguous pi writes.
__global__ __launch_bounds__(512)
void pass1_pi_kernel(const float* __restrict__ src, float* __restrict__ dst,
                     const float* __restrict__ angles, int blk_b) {
    __shared__ float lds[16384];
    const int tid  = threadIdx.x;
    const int lane = tid & 63;
    const int w    = tid >> 6;
    const int blk  = blockIdx.x;                 // e6..14
    const float* ang = angles + blk_b * N_QUBITS;
    const size_t lowbase = ((size_t)blk << 6) | (size_t)lane;

    float a[64];
#pragma unroll
    for (int r = 0; r < 64; ++r)
        a[r] = src[((size_t)((r << 3) | w) << 15) | lowbase];

    float s, c;
    sincosf(0.5f * ang[0], &s, &c); pair_bit<5>(a, s, c, 0);
    sincosf(0.5f * ang[1], &s, &c); quad_gate<4>(a, s, c);
    sincosf(0.5f * ang[2], &s, &c); quad_gate<3>(a, s, c);
    sincosf(0.5f * ang[3], &s, &c); quad_gate<2>(a, s, c);
    sincosf(0.5f * ang[4], &s, &c); quad_gate<1>(a, s, c);
    sincosf(0.5f * ang[5], &s, &c); quad_gate<0>(a, s, c);

#pragma unroll
    for (int cb = 0; cb < 2; ++cb) {
        if (cb) __syncthreads();
#pragma unroll
        for (int rr = 0; rr < 32; ++rr)
            lds[(rr << 9) | (w << 6) | lane] = a[(cb << 5) | rr];
        __syncthreads();
#pragma unroll
        for (int q = 0; q < 32; ++q) {
            int h = (((q >> 1) & 1) << 13) | ((q & 1) << 12) | (w << 9)
                  | (((q >> 4) & 1) << 8) | (((q >> 3) & 1) << 7) | (((q >> 2) & 1) << 6)
                  | lane;
            a[(cb << 5) | q] = lds[h];
        }
    }

    sincosf(0.5f * ang[6], &s, &c); pair_bit<4>(a, s, c, w & 1);
    sincosf(0.5f * ang[7], &s, &c); quad_gate<3>(a, s, c);
    sincosf(0.5f * ang[8], &s, &c); quad_gate<2>(a, s, c);

#pragma unroll
    for (int r = 0; r < 64; ++r) {
        int H = (((r >> 5) & 1) << 8) | (((r >> 1) & 1) << 7) | ((r & 1) << 6) | (w << 3)
              | (((r >> 4) & 1) << 2) | (((r >> 3) & 1) << 1) | ((r >> 2) & 1);
        dst[((size_t)blk << 15) | (H << 6) | lane] = a[r];
    }
}

// ---------------- Pass 2+3 tail: qubits 9..23 on a 32768-float chunk -----------
template <bool SQUARE>
__device__ __forceinline__ void p23_tail(float (&a)[64], float* __restrict__ lds,
                                         float* __restrict__ base, const float* ang,
                                         int lane, int w, int c15) {
    float s, c;
    // phase 1 (L0 regs: bit i = e9+i for i<5, bit5 = e14)
    sincosf(0.5f * ang[9], &s, &c);  pair_bit<5>(a, s, c, c15);   // q9: tgt e14, ctrl e15
    sincosf(0.5f * ang[10], &s, &c); quad_gate<4>(a, s, c);       // q10: tgt e13 ctrl e14
    sincosf(0.5f * ang[11], &s, &c); quad_gate<3>(a, s, c);
    sincosf(0.5f * ang[12], &s, &c); quad_gate<2>(a, s, c);
    sincosf(0.5f * ang[13], &s, &c); quad_gate<1>(a, s, c);
    sincosf(0.5f * ang[14], &s, &c); quad_gate<0>(a, s, c);       // q14: tgt e9 ctrl e10

    // T1: L0 -> L1, chunked by e14 (reg bit 5 both sides). Moving bits e0..e13.
    // addr: b0..4 = (e0..4)^(e9..13), b5 = e5, b6..8 = e6..8, b9..13 = e9..13.
    {
        const int Bw = (lane & 31) | ((lane >> 5) << 5) | (w << 6);
        const int Br = (w ^ (lane & 31)) | ((lane >> 5) << 8) | ((lane & 31) << 9);
#pragma unroll
        for (int x = 0; x < 2; ++x) {
            if (x) __syncthreads();
#pragma unroll
            for (int j = 0; j < 32; ++j)
                lds[(Bw ^ j) | (j << 9)] = a[(x << 5) | j];
            __syncthreads();
#pragma unroll
            for (int k = 0; k < 32; ++k)
                a[(x << 5) | k] = lds[(Br ^ ((k & 3) << 3)) | (((k >> 2) & 7) << 5)];
        }
    }

    // phase 2 (L1 regs: bit i = e3+i for i<5, bit5 = e14; lane: e9..13 + e8@bit5; w = e0..2)
    // q15: RY tgt e8 (lane bit 5) + CNOT ctrl e9 (lane bit 0): shfl gate
    sincosf(0.5f * ang[15], &s, &c);
    {
        const int hi  = (lane >> 5) & 1;      // e8
        const int sel = hi ^ (lane & 1);      // position after conditional swap
#pragma unroll
        for (int r = 0; r < 64; ++r) {
            float v = a[r], p = __shfl_xor(a[r], 32);
            float v0 = hi ? p : v, v1 = hi ? v : p;
            float o0 = c * v0 - s * v1;
            float o1 = s * v0 + c * v1;
            a[r] = sel ? o1 : o0;
        }
    }
    sincosf(0.5f * ang[16], &s, &c); pair_bit<4>(a, s, c, (lane >> 5) & 1); // q16: tgt e7, ctrl e8
    sincosf(0.5f * ang[17], &s, &c); quad_gate<3>(a, s, c);                 // q17: tgt e6 ctrl e7
    sincosf(0.5f * ang[18], &s, &c); quad_gate<2>(a, s, c);
    sincosf(0.5f * ang[19], &s, &c); quad_gate<1>(a, s, c);
    sincosf(0.5f * ang[20], &s, &c); quad_gate<0>(a, s, c);                 // q20: tgt e3 ctrl e4

    // T2: L1 -> L2, chunked by e14 (reg bit 5 both sides). Moving bits e0..e13.
    // addr: b0=e8, b1=e9, b2=e10, b3=e11^e5, b4=e12^e6; e0..2@5..7, e3,e4@8..9,
    //       e5..7@10..12, e13@13.
    {
        const int Wb = ((lane >> 5) & 1) | ((lane & 1) << 1) | (((lane >> 1) & 1) << 2)
                     | (((lane >> 2) & 1) << 3) | (((lane >> 3) & 1) << 4)
                     | (w << 5) | (((lane >> 4) & 1) << 13);
        const int Rb = ((lane >> 3) & 1) | (((lane >> 4) & 1) << 1) | (((lane >> 5) & 1) << 2)
                     | (((w & 1) ^ (lane & 1)) << 3) | ((((w >> 1) & 1) ^ ((lane >> 1) & 1)) << 4)
                     | ((lane & 7) << 10) | (((w >> 2) & 1) << 13);
#pragma unroll
        for (int x = 0; x < 2; ++x) {
            __syncthreads();
#pragma unroll
            for (int k = 0; k < 32; ++k) {
                int addr = (Wb ^ (((( k >> 2) & 1) << 3) | (((k >> 3) & 1) << 4)))
                         | ((k & 3) << 8) | (((k >> 2) & 7) << 10);
                lds[addr] = a[(x << 5) | k];
            }
            __syncthreads();
#pragma unroll
            for (int p = 0; p < 32; ++p)
                a[(x << 5) | p] = lds[Rb | ((p & 7) << 5) | (((p >> 3) & 3) << 8)];
        }
    }

    // phase 3 (L2 regs: bit i = e_i for i<5, bit5 = e14)
    sincosf(0.5f * ang[21], &s, &c); quad_gate<2>(a, s, c);   // q21: tgt e2 ctrl e3
    sincosf(0.5f * ang[22], &s, &c); quad_gate<1>(a, s, c);
    sincosf(0.5f * ang[23], &s, &c); quad_gate<0>(a, s, c);

    if (SQUARE) {
#pragma unroll
        for (int r = 0; r < 64; ++r) a[r] *= a[r];
    }

    // T3: L2 -> L3, chunked by e12 (w bit 1 both sides). Moving bits
    // {e0..e11, e13, e14}. addr: b0=e5, b1=e6^e0, b2=e7^e1, b3=e8^e2, b4=e9^e3;
    // e0..3@5..8, e4@9, e10@10, e11@11, e13@12, e14@13.
    {
        const int me = (w >> 1) & 1;
        const int Wb = (lane & 1) | (((lane >> 1) & 1) << 1) | (((lane >> 2) & 1) << 2)
                     | (((lane >> 3) & 1) << 3) | (((lane >> 4) & 1) << 4)
                     | ((lane >> 5) << 10) | ((w & 1) << 11) | (((w >> 2) & 1) << 12);
        const int Rb = ((lane >> 5) & 1) | ((lane & 1) << 1) | (((lane >> 1) & 1) << 2)
                     | (((lane >> 2) & 1) << 3) | (((lane >> 3) & 1) << 4)
                     | ((lane & 15) << 5) | (((lane >> 4) & 1) << 9)
                     | (((w >> 2) & 1) << 12) | ((w & 1) << 13);
#pragma unroll
        for (int x = 0; x < 2; ++x) {
            __syncthreads();
            if (me == x) {
#pragma unroll
                for (int r = 0; r < 64; ++r) {
                    int addr = (Wb ^ ((r & 15) << 1))
                             | ((r & 15) << 5) | (((r >> 4) & 1) << 9) | (((r >> 5) & 1) << 13);
                    lds[addr] = a[r];
                }
            }
            __syncthreads();
            if (me == x) {
#pragma unroll
                for (int q = 0; q < 64; ++q) {
                    int addr = (Rb ^ ((q & 15) << 1))
                             | (((q >> 4) & 1) << 10) | (((q >> 5) & 1) << 11);
                    a[q] = lds[addr];
                }
            }
        }
    }

    // store STANDARD (L3: lane = e0..5, regs q = e6..11, w = (e14, e12, e13))
#pragma unroll
    for (int q = 0; q < 64; ++q)
        base[lane | (q << 6) | (((w >> 1) & 1) << 12) | (((w >> 2) & 1) << 13)
             | ((w & 1) << 14)] = a[q];
}

// P23: read pi from src, write standard to dst.
template <bool SQUARE>
__global__ __launch_bounds__(512, 4)
void pass23_pi_kernel(const float* __restrict__ src, float* __restrict__ dst,
                      const float* __restrict__ angles, int blk_b) {
    __shared__ float lds[16384];
    const int tid  = threadIdx.x;
    const int lane = tid & 63;
    const int w    = tid >> 6;
    const int chunk = blockIdx.x;                // = H = e15..23
    float* __restrict__ base = dst + ((size_t)chunk << 15);
    const int c15 = chunk & 1;                   // e15
    const float* ang = angles + blk_b * N_QUBITS;

    float a[64];
    // read pi: addr = (B = e6..14 = r<<3|w)<<15 | chunk<<6 | lane  (L0 entry layout)
#pragma unroll
    for (int r = 0; r < 64; ++r)
        a[r] = src[((size_t)((r << 3) | w) << 15) | ((size_t)chunk << 6) | (size_t)lane];

    p23_tail<SQUARE>(a, lds, base, ang, lane, w, c15);
}

// Block 0 fused: after qubits 0..8 from |0..0>, state = f9[e15..23] * delta(e0..14).
__global__ __launch_bounds__(512, 4)
void pass23_init_kernel(float* __restrict__ dst, const float* __restrict__ angles) {
    __shared__ float lds[16384];
    const int tid  = threadIdx.x;
    const int lane = tid & 63;
    const int w    = tid >> 6;
    const int chunk = blockIdx.x;
    float* __restrict__ base = dst + ((size_t)chunk << 15);
    const float* ang = angles;                   // block 0
    float s, c;

    float* f = lds;
    f[tid] = 0.0f;
    __syncthreads();
    if (tid == 0) f[0] = 1.0f;
    __syncthreads();
    sincosf(0.5f * ang[0], &s, &c);
    if (tid < 256) {
        float v0 = f[tid], v1 = f[tid | 256];
        f[tid]       = c * v0 - s * v1;
        f[tid | 256] = s * v0 + c * v1;
    }
    __syncthreads();
    for (int q = 1; q <= 8; ++q) {
        sincosf(0.5f * ang[q], &s, &c);
        int bt = 8 - q;
        if (tid < 128) {
            int lo  = tid & ((1 << bt) - 1);
            int r00 = ((tid >> bt) << (bt + 2)) | lo;
            int r01 = r00 | (1 << bt);
            int r10 = r00 | (2 << bt);
            int r11 = r00 | (3 << bt);
            float v00 = f[r00], v01 = f[r01], v10 = f[r10], v11 = f[r11];
            f[r00] = c * v00 - s * v01;
            f[r01] = s * v00 + c * v01;
            f[r10] = s * v10 + c * v11;
            f[r11] = c * v10 - s * v11;
        }
        __syncthreads();
    }
    const float amp = f[chunk];
    __syncthreads();                             // lds reused by the tail

    float a[64];
#pragma unroll
    for (int r = 0; r < 64; ++r) a[r] = 0.0f;
    if (tid == 0) a[0] = amp;                    // h = 0 -> r = 0, w = 0, lane = 0

    p23_tail<false>(a, lds, base, ang, lane, w, chunk & 1);
}

extern "C" void kernel_launch(void* const* d_in, const int* in_sizes, int n_in,
                              void* d_out, int out_size, void* d_ws, size_t ws_size,
                              hipStream_t stream) {
    const float* angles = (const float*)d_in[0];
    float* out = (float*)d_out;
    float* ws  = (float*)d_ws;

    pass23_init_kernel<<<NSTATE >> 15, 512, 0, stream>>>(out, angles);

    for (int b = 1; b < N_BLOCKS; ++b) {
        const bool last = (b == N_BLOCKS - 1);
        pass1_pi_kernel<<<NSTATE >> 15, 512, 0, stream>>>(out, ws, angles, b);
        if (last)
            pass23_pi_kernel<true><<<NSTATE >> 15, 512, 0, stream>>>(ws, out, angles, b);
        else
            pass23_pi_kernel<false><<<NSTATE >> 15, 512, 0, stream>>>(ws, out, angles, b);
    }
}

// Round 8
// 286.396 us; speedup vs baseline: 1.0013x; 1.0013x over previous
//
#include <hip/hip_runtime.h>
#include <math.h>

#define N_QUBITS 24
#define N_BLOCKS 4
#define NSTATE (1 << N_QUBITS)

// Qubit q <-> flat-index bit (23 - q).
// Per block (by commutation): RY(0); for q=1..23: RY(q); CNOT(q-1,q)
// Ping-pong buffers, alternating layouts (race-free: src != dst).
//   standard: addr = e23..e0
//   pi:       addr = e[6..14]<<15 | H<<6 | e[0..5],  H bit k = e(15+k)
// P1  (qubits 0..8):  d_out std (scattered 256B reads) -> d_ws pi (contiguous)
// P23 (qubits 9..23): d_ws pi (scattered 256B reads) -> d_out std (contiguous)
// P23: 512 thr, 64 regs, LDS 64 KiB (2 wg/CU). Three transposes, each chunked
// into 2 rounds of 16K floats; split bit holds the SAME register/w position on
// both sides of each transpose -> rounds are clobber-free (no temp registers).
// NOTE: no min-blocks arg in __launch_bounds__ — (512,4) forced VGPR<=64 and
// spilled a[64] to scratch (R7: FETCH+WRITE 2x, init 60us). LDS=64KiB already
// yields 2 blocks/CU.

// ---- 64-reg gate helpers ----
template <int B>
__device__ __forceinline__ void pair_bit(float (&a)[64], float s, float c, int swap) {
#pragma unroll
    for (int g = 0; g < 32; ++g) {
        int r0 = ((g >> B) << (B + 1)) | (g & ((1 << B) - 1));
        int r1 = r0 | (1 << B);
        float v0 = a[r0], v1 = a[r1];
        float o0 = c * v0 - s * v1;
        float o1 = s * v0 + c * v1;
        a[r0] = swap ? o1 : o0;
        a[r1] = swap ? o0 : o1;
    }
}
// Fused RY(tgt = reg bit BT) then CNOT(ctrl = reg bit BT+1, tgt = reg bit BT).
template <int BT>
__device__ __forceinline__ void quad_gate(float (&a)[64], float s, float c) {
#pragma unroll
    for (int g = 0; g < 16; ++g) {
        int lo  = g & ((1 << BT) - 1);
        int r00 = ((g >> BT) << (BT + 2)) | lo;
        int r01 = r00 | (1 << BT);
        int r10 = r00 | (2 << BT);
        int r11 = r00 | (3 << BT);
        float v00 = a[r00], v01 = a[r01], v10 = a[r10], v11 = a[r11];
        a[r00] = c * v00 - s * v01;
        a[r01] = s * v00 + c * v01;
        a[r10] = s * v10 + c * v11;   // ctrl=1 half: RY then swap (CNOT)
        a[r11] = c * v10 - s * v11;
    }
}

// ---------------- Pass 1 (std -> pi): qubits 0..8 (bits 15..23) ----------------
// Proven ~32 us. 512 thr, 64 KiB LDS, contiguous pi writes.
__global__ __launch_bounds__(512)
void pass1_pi_kernel(const float* __restrict__ src, float* __restrict__ dst,
                     const float* __restrict__ angles, int blk_b) {
    __shared__ float lds[16384];
    const int tid  = threadIdx.x;
    const int lane = tid & 63;
    const int w    = tid >> 6;
    const int blk  = blockIdx.x;                 // e6..14
    const float* ang = angles + blk_b * N_QUBITS;
    const size_t lowbase = ((size_t)blk << 6) | (size_t)lane;

    float a[64];
#pragma unroll
    for (int r = 0; r < 64; ++r)
        a[r] = src[((size_t)((r << 3) | w) << 15) | lowbase];

    float s, c;
    sincosf(0.5f * ang[0], &s, &c); pair_bit<5>(a, s, c, 0);
    sincosf(0.5f * ang[1], &s, &c); quad_gate<4>(a, s, c);
    sincosf(0.5f * ang[2], &s, &c); quad_gate<3>(a, s, c);
    sincosf(0.5f * ang[3], &s, &c); quad_gate<2>(a, s, c);
    sincosf(0.5f * ang[4], &s, &c); quad_gate<1>(a, s, c);
    sincosf(0.5f * ang[5], &s, &c); quad_gate<0>(a, s, c);

#pragma unroll
    for (int cb = 0; cb < 2; ++cb) {
        if (cb) __syncthreads();
#pragma unroll
        for (int rr = 0; rr < 32; ++rr)
            lds[(rr << 9) | (w << 6) | lane] = a[(cb << 5) | rr];
        __syncthreads();
#pragma unroll
        for (int q = 0; q < 32; ++q) {
            int h = (((q >> 1) & 1) << 13) | ((q & 1) << 12) | (w << 9)
                  | (((q >> 4) & 1) << 8) | (((q >> 3) & 1) << 7) | (((q >> 2) & 1) << 6)
                  | lane;
            a[(cb << 5) | q] = lds[h];
        }
    }

    sincosf(0.5f * ang[6], &s, &c); pair_bit<4>(a, s, c, w & 1);
    sincosf(0.5f * ang[7], &s, &c); quad_gate<3>(a, s, c);
    sincosf(0.5f * ang[8], &s, &c); quad_gate<2>(a, s, c);

#pragma unroll
    for (int r = 0; r < 64; ++r) {
        int H = (((r >> 5) & 1) << 8) | (((r >> 1) & 1) << 7) | ((r & 1) << 6) | (w << 3)
              | (((r >> 4) & 1) << 2) | (((r >> 3) & 1) << 1) | ((r >> 2) & 1);
        dst[((size_t)blk << 15) | (H << 6) | lane] = a[r];
    }
}

// ---------------- Pass 2+3 tail: qubits 9..23 on a 32768-float chunk -----------
// Layouts:
//   L0: regs=(e9..e13, e14@bit5), w=e6..8, lane=e0..5      [entry]
//   T1 (split e14) -> L1: regs=(e3..e7, e14@bit5), lane=(e9..e13, e8@bit5), w=e0..2
//   T2 (split e14) -> L2: regs=(e0..e4, e14@bit5), lane=e5..10, w=(e11,e12,e13)
//   T3 (split e12=w bit1) -> L3: regs=e6..11, lane=e0..5, w=(e14,e12,e13)
template <bool SQUARE>
__device__ __forceinline__ void p23_tail(float (&a)[64], float* __restrict__ lds,
                                         float* __restrict__ base, const float* ang,
                                         int lane, int w, int c15) {
    float s, c;
    // phase 1 (L0 regs: bit i = e9+i for i<5, bit5 = e14)
    sincosf(0.5f * ang[9], &s, &c);  pair_bit<5>(a, s, c, c15);   // q9: tgt e14, ctrl e15
    sincosf(0.5f * ang[10], &s, &c); quad_gate<4>(a, s, c);       // q10: tgt e13 ctrl e14
    sincosf(0.5f * ang[11], &s, &c); quad_gate<3>(a, s, c);
    sincosf(0.5f * ang[12], &s, &c); quad_gate<2>(a, s, c);
    sincosf(0.5f * ang[13], &s, &c); quad_gate<1>(a, s, c);
    sincosf(0.5f * ang[14], &s, &c); quad_gate<0>(a, s, c);       // q14: tgt e9 ctrl e10

    // T1: L0 -> L1, chunked by e14 (reg bit 5 both sides). Moving bits e0..e13.
    // addr: b0..4 = (e0..4)^(e9..13), b5 = e5, b6..8 = e6..8, b9..13 = e9..13.
    {
        const int Bw = (lane & 31) | ((lane >> 5) << 5) | (w << 6);
        const int Br = (w ^ (lane & 31)) | ((lane >> 5) << 8) | ((lane & 31) << 9);
#pragma unroll
        for (int x = 0; x < 2; ++x) {
            if (x) __syncthreads();
#pragma unroll
            for (int j = 0; j < 32; ++j)
                lds[(Bw ^ j) | (j << 9)] = a[(x << 5) | j];
            __syncthreads();
#pragma unroll
            for (int k = 0; k < 32; ++k)
                a[(x << 5) | k] = lds[(Br ^ ((k & 3) << 3)) | (((k >> 2) & 7) << 5)];
        }
    }

    // phase 2 (L1 regs: bit i = e3+i for i<5, bit5 = e14; lane: e9..13 + e8@bit5; w = e0..2)
    // q15: RY tgt e8 (lane bit 5) + CNOT ctrl e9 (lane bit 0): shfl gate
    sincosf(0.5f * ang[15], &s, &c);
    {
        const int hi  = (lane >> 5) & 1;      // e8
        const int sel = hi ^ (lane & 1);      // position after conditional swap
#pragma unroll
        for (int r = 0; r < 64; ++r) {
            float v = a[r], p = __shfl_xor(a[r], 32);
            float v0 = hi ? p : v, v1 = hi ? v : p;
            float o0 = c * v0 - s * v1;
            float o1 = s * v0 + c * v1;
            a[r] = sel ? o1 : o0;
        }
    }
    sincosf(0.5f * ang[16], &s, &c); pair_bit<4>(a, s, c, (lane >> 5) & 1); // q16: tgt e7, ctrl e8
    sincosf(0.5f * ang[17], &s, &c); quad_gate<3>(a, s, c);                 // q17: tgt e6 ctrl e7
    sincosf(0.5f * ang[18], &s, &c); quad_gate<2>(a, s, c);
    sincosf(0.5f * ang[19], &s, &c); quad_gate<1>(a, s, c);
    sincosf(0.5f * ang[20], &s, &c); quad_gate<0>(a, s, c);                 // q20: tgt e3 ctrl e4

    // T2: L1 -> L2, chunked by e14 (reg bit 5 both sides). Moving bits e0..e13.
    {
        const int Wb = ((lane >> 5) & 1) | ((lane & 1) << 1) | (((lane >> 1) & 1) << 2)
                     | (((lane >> 2) & 1) << 3) | (((lane >> 3) & 1) << 4)
                     | (w << 5) | (((lane >> 4) & 1) << 13);
        const int Rb = ((lane >> 3) & 1) | (((lane >> 4) & 1) << 1) | (((lane >> 5) & 1) << 2)
                     | (((w & 1) ^ (lane & 1)) << 3) | ((((w >> 1) & 1) ^ ((lane >> 1) & 1)) << 4)
                     | ((lane & 7) << 10) | (((w >> 2) & 1) << 13);
#pragma unroll
        for (int x = 0; x < 2; ++x) {
            __syncthreads();
#pragma unroll
            for (int k = 0; k < 32; ++k) {
                int addr = (Wb ^ (((( k >> 2) & 1) << 3) | (((k >> 3) & 1) << 4)))
                         | ((k & 3) << 8) | (((k >> 2) & 7) << 10);
                lds[addr] = a[(x << 5) | k];
            }
            __syncthreads();
#pragma unroll
            for (int p = 0; p < 32; ++p)
                a[(x << 5) | p] = lds[Rb | ((p & 7) << 5) | (((p >> 3) & 3) << 8)];
        }
    }

    // phase 3 (L2 regs: bit i = e_i for i<5, bit5 = e14)
    sincosf(0.5f * ang[21], &s, &c); quad_gate<2>(a, s, c);   // q21: tgt e2 ctrl e3
    sincosf(0.5f * ang[22], &s, &c); quad_gate<1>(a, s, c);
    sincosf(0.5f * ang[23], &s, &c); quad_gate<0>(a, s, c);

    if (SQUARE) {
#pragma unroll
        for (int r = 0; r < 64; ++r) a[r] *= a[r];
    }

    // T3: L2 -> L3, chunked by e12 (w bit 1 both sides).
    {
        const int me = (w >> 1) & 1;
        const int Wb = (lane & 1) | (((lane >> 1) & 1) << 1) | (((lane >> 2) & 1) << 2)
                     | (((lane >> 3) & 1) << 3) | (((lane >> 4) & 1) << 4)
                     | ((lane >> 5) << 10) | ((w & 1) << 11) | (((w >> 2) & 1) << 12);
        const int Rb = ((lane >> 5) & 1) | ((lane & 1) << 1) | (((lane >> 1) & 1) << 2)
                     | (((lane >> 2) & 1) << 3) | (((lane >> 3) & 1) << 4)
                     | ((lane & 15) << 5) | (((lane >> 4) & 1) << 9)
                     | (((w >> 2) & 1) << 12) | ((w & 1) << 13);
#pragma unroll
        for (int x = 0; x < 2; ++x) {
            __syncthreads();
            if (me == x) {
#pragma unroll
                for (int r = 0; r < 64; ++r) {
                    int addr = (Wb ^ ((r & 15) << 1))
                             | ((r & 15) << 5) | (((r >> 4) & 1) << 9) | (((r >> 5) & 1) << 13);
                    lds[addr] = a[r];
                }
            }
            __syncthreads();
            if (me == x) {
#pragma unroll
                for (int q = 0; q < 64; ++q) {
                    int addr = (Rb ^ ((q & 15) << 1))
                             | (((q >> 4) & 1) << 10) | (((q >> 5) & 1) << 11);
                    a[q] = lds[addr];
                }
            }
        }
    }

    // store STANDARD (L3: lane = e0..5, regs q = e6..11, w = (e14, e12, e13))
#pragma unroll
    for (int q = 0; q < 64; ++q)
        base[lane | (q << 6) | (((w >> 1) & 1) << 12) | (((w >> 2) & 1) << 13)
             | ((w & 1) << 14)] = a[q];
}

// P23: read pi from src, write standard to dst.
template <bool SQUARE>
__global__ __launch_bounds__(512)
void pass23_pi_kernel(const float* __restrict__ src, float* __restrict__ dst,
                      const float* __restrict__ angles, int blk_b) {
    __shared__ float lds[16384];
    const int tid  = threadIdx.x;
    const int lane = tid & 63;
    const int w    = tid >> 6;
    const int chunk = blockIdx.x;                // = H = e15..23
    float* __restrict__ base = dst + ((size_t)chunk << 15);
    const int c15 = chunk & 1;                   // e15
    const float* ang = angles + blk_b * N_QUBITS;

    float a[64];
    // read pi: addr = (B = e6..14 = r<<3|w)<<15 | chunk<<6 | lane  (L0 entry layout)
#pragma unroll
    for (int r = 0; r < 64; ++r)
        a[r] = src[((size_t)((r << 3) | w) << 15) | ((size_t)chunk << 6) | (size_t)lane];

    p23_tail<SQUARE>(a, lds, base, ang, lane, w, c15);
}

// Block 0 fused: after qubits 0..8 from |0..0>, state = f9[e15..23] * delta(e0..14).
__global__ __launch_bounds__(512)
void pass23_init_kernel(float* __restrict__ dst, const float* __restrict__ angles) {
    __shared__ float lds[16384];
    const int tid  = threadIdx.x;
    const int lane = tid & 63;
    const int w    = tid >> 6;
    const int chunk = blockIdx.x;
    float* __restrict__ base = dst + ((size_t)chunk << 15);
    const float* ang = angles;                   // block 0
    float s, c;

    float* f = lds;
    f[tid] = 0.0f;
    __syncthreads();
    if (tid == 0) f[0] = 1.0f;
    __syncthreads();
    sincosf(0.5f * ang[0], &s, &c);
    if (tid < 256) {
        float v0 = f[tid], v1 = f[tid | 256];
        f[tid]       = c * v0 - s * v1;
        f[tid | 256] = s * v0 + c * v1;
    }
    __syncthreads();
    for (int q = 1; q <= 8; ++q) {
        sincosf(0.5f * ang[q], &s, &c);
        int bt = 8 - q;
        if (tid < 128) {
            int lo  = tid & ((1 << bt) - 1);
            int r00 = ((tid >> bt) << (bt + 2)) | lo;
            int r01 = r00 | (1 << bt);
            int r10 = r00 | (2 << bt);
            int r11 = r00 | (3 << bt);
            float v00 = f[r00], v01 = f[r01], v10 = f[r10], v11 = f[r11];
            f[r00] = c * v00 - s * v01;
            f[r01] = s * v00 + c * v01;
            f[r10] = s * v10 + c * v11;
            f[r11] = c * v10 - s * v11;
        }
        __syncthreads();
    }
    const float amp = f[chunk];
    __syncthreads();                             // lds reused by the tail

    float a[64];
#pragma unroll
    for (int r = 0; r < 64; ++r) a[r] = 0.0f;
    if (tid == 0) a[0] = amp;                    // h = 0 -> r = 0, w = 0, lane = 0

    p23_tail<false>(a, lds, base, ang, lane, w, chunk & 1);
}

extern "C" void kernel_launch(void* const* d_in, const int* in_sizes, int n_in,
                              void* d_out, int out_size, void* d_ws, size_t ws_size,
                              hipStream_t stream) {
    const float* angles = (const float*)d_in[0];
    float* out = (float*)d_out;
    float* ws  = (float*)d_ws;

    pass23_init_kernel<<<NSTATE >> 15, 512, 0, stream>>>(out, angles);

    for (int b = 1; b < N_BLOCKS; ++b) {
        const bool last = (b == N_BLOCKS - 1);
        pass1_pi_kernel<<<NSTATE >> 15, 512, 0, stream>>>(out, ws, angles, b);
        if (last)
            pass23_pi_kernel<true><<<NSTATE >> 15, 512, 0, stream>>>(ws, out, angles, b);
        else
            pass23_pi_kernel<false><<<NSTATE >> 15, 512, 0, stream>>>(ws, out, angles, b);
    }
}

// Round 9
// 258.722 us; speedup vs baseline: 1.1084x; 1.1070x over previous
//
#include <hip/hip_runtime.h>
#include <math.h>

#define N_QUBITS 24
#define N_BLOCKS 4
#define NSTATE (1 << N_QUBITS)

// Qubit q <-> flat-index bit (23 - q).
// Per block (by commutation): RY(0); for q=1..23: RY(q); CNOT(q-1,q)
// Ping-pong buffers, alternating layouts (race-free: src != dst).
//   standard: addr = e23..e0
//   pi:       addr = e[6..14]<<15 | H<<6 | e[0..5],  H bit k = e(15+k)
// P1  (qubits 0..8):  d_out std (scattered 256B reads) -> d_ws pi (contiguous)
// P23 (qubits 9..23): d_ws pi (scattered 256B reads) -> d_out std (contiguous)
// P23 internals (R9): ONE e14-chunked transpose (64 KiB LDS, 3 barriers),
// qubits 15..17 as reg-gates after it, qubits 18..23 as lane shfl-gates
// (fused RY+CNOT = 1 shfl_xor + mul/fma per reg). T2/T3 deleted.

// ---- 64-reg gate helpers ----
template <int B>
__device__ __forceinline__ void pair_bit(float (&a)[64], float s, float c, int swap) {
#pragma unroll
    for (int g = 0; g < 32; ++g) {
        int r0 = ((g >> B) << (B + 1)) | (g & ((1 << B) - 1));
        int r1 = r0 | (1 << B);
        float v0 = a[r0], v1 = a[r1];
        float o0 = c * v0 - s * v1;
        float o1 = s * v0 + c * v1;
        a[r0] = swap ? o1 : o0;
        a[r1] = swap ? o0 : o1;
    }
}
// Fused RY(tgt = reg bit BT) then CNOT(ctrl = reg bit BT+1, tgt = reg bit BT).
template <int BT>
__device__ __forceinline__ void quad_gate(float (&a)[64], float s, float c) {
#pragma unroll
    for (int g = 0; g < 16; ++g) {
        int lo  = g & ((1 << BT) - 1);
        int r00 = ((g >> BT) << (BT + 2)) | lo;
        int r01 = r00 | (1 << BT);
        int r10 = r00 | (2 << BT);
        int r11 = r00 | (3 << BT);
        float v00 = a[r00], v01 = a[r01], v10 = a[r10], v11 = a[r11];
        a[r00] = c * v00 - s * v01;
        a[r01] = s * v00 + c * v01;
        a[r10] = s * v10 + c * v11;   // ctrl=1 half: RY then swap (CNOT)
        a[r11] = c * v10 - s * v11;
    }
}

// ---------------- Pass 1 (std -> pi): qubits 0..8 (bits 15..23) ----------------
// Proven ~32 us. 512 thr, 64 KiB LDS, contiguous pi writes. Unchanged.
__global__ __launch_bounds__(512)
void pass1_pi_kernel(const float* __restrict__ src, float* __restrict__ dst,
                     const float* __restrict__ angles, int blk_b) {
    __shared__ float lds[16384];
    const int tid  = threadIdx.x;
    const int lane = tid & 63;
    const int w    = tid >> 6;
    const int blk  = blockIdx.x;                 // e6..14
    const float* ang = angles + blk_b * N_QUBITS;
    const size_t lowbase = ((size_t)blk << 6) | (size_t)lane;

    float a[64];
#pragma unroll
    for (int r = 0; r < 64; ++r)
        a[r] = src[((size_t)((r << 3) | w) << 15) | lowbase];

    float s, c;
    sincosf(0.5f * ang[0], &s, &c); pair_bit<5>(a, s, c, 0);
    sincosf(0.5f * ang[1], &s, &c); quad_gate<4>(a, s, c);
    sincosf(0.5f * ang[2], &s, &c); quad_gate<3>(a, s, c);
    sincosf(0.5f * ang[3], &s, &c); quad_gate<2>(a, s, c);
    sincosf(0.5f * ang[4], &s, &c); quad_gate<1>(a, s, c);
    sincosf(0.5f * ang[5], &s, &c); quad_gate<0>(a, s, c);

#pragma unroll
    for (int cb = 0; cb < 2; ++cb) {
        if (cb) __syncthreads();
#pragma unroll
        for (int rr = 0; rr < 32; ++rr)
            lds[(rr << 9) | (w << 6) | lane] = a[(cb << 5) | rr];
        __syncthreads();
#pragma unroll
        for (int q = 0; q < 32; ++q) {
            int h = (((q >> 1) & 1) << 13) | ((q & 1) << 12) | (w << 9)
                  | (((q >> 4) & 1) << 8) | (((q >> 3) & 1) << 7) | (((q >> 2) & 1) << 6)
                  | lane;
            a[(cb << 5) | q] = lds[h];
        }
    }

    sincosf(0.5f * ang[6], &s, &c); pair_bit<4>(a, s, c, w & 1);
    sincosf(0.5f * ang[7], &s, &c); quad_gate<3>(a, s, c);
    sincosf(0.5f * ang[8], &s, &c); quad_gate<2>(a, s, c);

#pragma unroll
    for (int r = 0; r < 64; ++r) {
        int H = (((r >> 5) & 1) << 8) | (((r >> 1) & 1) << 7) | ((r & 1) << 6) | (w << 3)
              | (((r >> 4) & 1) << 2) | (((r >> 3) & 1) << 1) | ((r >> 2) & 1);
        dst[((size_t)blk << 15) | (H << 6) | lane] = a[r];
    }
}

// ---------------- Pass 2+3 tail: qubits 9..23 on a 32768-float chunk -----------
// L0 (entry): regs = (e9..e13, e14@bit5), w = e6..8, lane = e0..5.
// T1 (chunked by e14, reg bit5 both sides):
//   L1: regs = (e6,e7,e8,e9,e10, e14@bit5), w = e11..13, lane = e0..5.
// Gates: q9..14 reg (L0); q15..17 reg (L1); q18..23 lane shfl-gates.
// Store std directly from L1 (contiguous 256B/wave-instr).
template <bool SQUARE>
__device__ __forceinline__ void p23_tail(float (&a)[64], float* __restrict__ lds,
                                         float* __restrict__ base, const float* ang,
                                         int lane, int w, int c15) {
    float s, c;
    // phase 1: qubits 9..14 on regs (bit i = e9+i for i<5, bit5 = e14)
    sincosf(0.5f * ang[9], &s, &c);  pair_bit<5>(a, s, c, c15);   // q9: tgt e14, ctrl e15
    sincosf(0.5f * ang[10], &s, &c); quad_gate<4>(a, s, c);       // q10: tgt e13 ctrl e14
    sincosf(0.5f * ang[11], &s, &c); quad_gate<3>(a, s, c);
    sincosf(0.5f * ang[12], &s, &c); quad_gate<2>(a, s, c);
    sincosf(0.5f * ang[13], &s, &c); quad_gate<1>(a, s, c);
    sincosf(0.5f * ang[14], &s, &c); quad_gate<0>(a, s, c);       // q14: tgt e9 ctrl e10

    // T1: chunked by e14 (reg bit5 both sides), 16K floats/round.
    // write: h = j<<9 | w<<6 | lane   (j = e9..13, w = e6..8)
    // read:  element (e6..8 = k&7, e9 = k3, e10 = k4, e11..13 = this w as w')
    //        -> h = ((k>>3)&3 | w<<2)<<9 | (k&7)<<6 | lane
    // Both sides: lanes consecutive -> 2-way bank access (free).
#pragma unroll
    for (int x = 0; x < 2; ++x) {
        if (x) __syncthreads();
#pragma unroll
        for (int j = 0; j < 32; ++j)
            lds[(j << 9) | (w << 6) | lane] = a[(x << 5) | j];
        __syncthreads();
#pragma unroll
        for (int k = 0; k < 32; ++k)
            a[(x << 5) | k] = lds[(((((k >> 3) & 3) | (w << 2)) << 9))
                                  | ((k & 7) << 6) | lane];
    }

    // phase 2: qubits 15..17 on L1 regs (k0=e6, k1=e7, k2=e8, k3=e9, k4=e10)
    sincosf(0.5f * ang[15], &s, &c); quad_gate<2>(a, s, c);   // q15: tgt e8, ctrl e9
    sincosf(0.5f * ang[16], &s, &c); quad_gate<1>(a, s, c);   // q16: tgt e7, ctrl e8
    sincosf(0.5f * ang[17], &s, &c); quad_gate<0>(a, s, c);   // q17: tgt e6, ctrl e7

    // phase 3: qubits 18..23 as lane shfl-gates.
    // Fused RY+CNOT butterfly: out = A*v + B*partner,
    //   gamma (ctrl bit) = 0: (A,B) = (c, tau? s : -s)
    //   gamma = 1:            (A,B) = (tau? -s : s, c)
    // q18: tgt e5 = lane bit5, ctrl e6 = reg bit0 (compile-time per reg)
    sincosf(0.5f * ang[18], &s, &c);
    {
        const int tau = (lane >> 5) & 1;
        const float A0 = c,              B0 = tau ? s : -s;   // gamma = 0
        const float A1 = tau ? -s : s,   B1 = c;              // gamma = 1
#pragma unroll
        for (int r = 0; r < 64; ++r) {
            float p = __shfl_xor(a[r], 32);
            float A = (r & 1) ? A1 : A0;
            float B = (r & 1) ? B1 : B0;
            a[r] = A * a[r] + B * p;
        }
    }
    // q19..q23: tgt = lane bit bt (4..0), ctrl = lane bit bt+1
#pragma unroll
    for (int q = 19; q <= 23; ++q) {
        const int bt = 23 - q;                 // 4..0
        sincosf(0.5f * ang[q], &s, &c);
        const int tau = (lane >> bt) & 1;
        const int gam = (lane >> (bt + 1)) & 1;
        const float A = gam ? (tau ? -s : s) : c;
        const float B = gam ? c : (tau ? s : -s);
#pragma unroll
        for (int r = 0; r < 64; ++r) {
            float p = __shfl_xor(a[r], 1 << bt);
            a[r] = A * a[r] + B * p;
        }
    }

    if (SQUARE) {
#pragma unroll
        for (int r = 0; r < 64; ++r) a[r] *= a[r];
    }

    // store STANDARD from L1: addr = e14<<14 | (e11..13=w)<<11 | (e6..10=k&31)<<6 | lane
#pragma unroll
    for (int k = 0; k < 64; ++k)
        base[(((k >> 5) & 1) << 14) | (w << 11) | ((k & 31) << 6) | lane] = a[k];
}

// P23: read pi from src, write standard to dst.
template <bool SQUARE>
__global__ __launch_bounds__(512)
void pass23_pi_kernel(const float* __restrict__ src, float* __restrict__ dst,
                      const float* __restrict__ angles, int blk_b) {
    __shared__ float lds[16384];
    const int tid  = threadIdx.x;
    const int lane = tid & 63;
    const int w    = tid >> 6;
    const int chunk = blockIdx.x;                // = H = e15..23
    float* __restrict__ base = dst + ((size_t)chunk << 15);
    const int c15 = chunk & 1;                   // e15
    const float* ang = angles + blk_b * N_QUBITS;

    float a[64];
    // read pi: addr = (e6..14 = r<<3|w)<<15 | chunk<<6 | lane  (L0 entry layout)
#pragma unroll
    for (int r = 0; r < 64; ++r)
        a[r] = src[((size_t)((r << 3) | w) << 15) | ((size_t)chunk << 6) | (size_t)lane];

    p23_tail<SQUARE>(a, lds, base, ang, lane, w, c15);
}

// Block 0 fused: after qubits 0..8 from |0..0>, state = f9[e15..23] * delta(e0..14).
__global__ __launch_bounds__(512)
void pass23_init_kernel(float* __restrict__ dst, const float* __restrict__ angles) {
    __shared__ float lds[16384];
    const int tid  = threadIdx.x;
    const int lane = tid & 63;
    const int w    = tid >> 6;
    const int chunk = blockIdx.x;
    float* __restrict__ base = dst + ((size_t)chunk << 15);
    const float* ang = angles;                   // block 0
    float s, c;

    float* f = lds;
    f[tid] = 0.0f;
    __syncthreads();
    if (tid == 0) f[0] = 1.0f;
    __syncthreads();
    sincosf(0.5f * ang[0], &s, &c);
    if (tid < 256) {
        float v0 = f[tid], v1 = f[tid | 256];
        f[tid]       = c * v0 - s * v1;
        f[tid | 256] = s * v0 + c * v1;
    }
    __syncthreads();
    for (int q = 1; q <= 8; ++q) {
        sincosf(0.5f * ang[q], &s, &c);
        int bt = 8 - q;
        if (tid < 128) {
            int lo  = tid & ((1 << bt) - 1);
            int r00 = ((tid >> bt) << (bt + 2)) | lo;
            int r01 = r00 | (1 << bt);
            int r10 = r00 | (2 << bt);
            int r11 = r00 | (3 << bt);
            float v00 = f[r00], v01 = f[r01], v10 = f[r10], v11 = f[r11];
            f[r00] = c * v00 - s * v01;
            f[r01] = s * v00 + c * v01;
            f[r10] = s * v10 + c * v11;
            f[r11] = c * v10 - s * v11;
        }
        __syncthreads();
    }
    const float amp = f[chunk];
    __syncthreads();                             // lds reused by the tail

    float a[64];
#pragma unroll
    for (int r = 0; r < 64; ++r) a[r] = 0.0f;
    if (tid == 0) a[0] = amp;                    // h = 0 -> r = 0, w = 0, lane = 0

    p23_tail<false>(a, lds, base, ang, lane, w, chunk & 1);
}

extern "C" void kernel_launch(void* const* d_in, const int* in_sizes, int n_in,
                              void* d_out, int out_size, void* d_ws, size_t ws_size,
                              hipStream_t stream) {
    const float* angles = (const float*)d_in[0];
    float* out = (float*)d_out;
    float* ws  = (float*)d_ws;

    pass23_init_kernel<<<NSTATE >> 15, 512, 0, stream>>>(out, angles);

    for (int b = 1; b < N_BLOCKS; ++b) {
        const bool last = (b == N_BLOCKS - 1);
        pass1_pi_kernel<<<NSTATE >> 15, 512, 0, stream>>>(out, ws, angles, b);
        if (last)
            pass23_pi_kernel<true><<<NSTATE >> 15, 512, 0, stream>>>(ws, out, angles, b);
        else
            pass23_pi_kernel<false><<<NSTATE >> 15, 512, 0, stream>>>(ws, out, angles, b);
    }
}

// Round 11
// 247.931 us; speedup vs baseline: 1.1567x; 1.0435x over previous
//
#include <hip/hip_runtime.h>
#include <math.h>

#define N_QUBITS 24
#define N_BLOCKS 4
#define NSTATE (1 << N_QUBITS)

// Qubit q <-> flat-index bit (23 - q).
// Per block (by commutation): RY(0); for q=1..23: RY(q); CNOT(q-1,q)
// Ping-pong buffers, alternating layouts (race-free: src != dst).
//   standard: addr = e23..e0
//   pi:       addr = e[6..14]<<15 | H<<6 | e[0..5],  H bit k = e(15+k)
// P1  (qubits 0..8):  d_out std (scattered reads) -> d_ws pi (contiguous)  [R9 proven]
// P23 (qubits 9..23): d_ws pi (scattered reads) -> d_out std (contiguous)
//     512 thr x 64 regs; ONE swizzled transpose to L1 regs=(e4..8,e14) so
//     q15..19 are reg gates and only q20..23 are shfl gates (masks 8/4/2/1).
// H is identity-ordered (H_k = e15+k) so pass23's output base = chunk<<15 IS
// standard layout (R10's permuted X broke exactly this).

// ---- 64-reg gate helpers ----
template <int B>
__device__ __forceinline__ void pair_bit(float (&a)[64], float s, float c, int swap) {
#pragma unroll
    for (int g = 0; g < 32; ++g) {
        int r0 = ((g >> B) << (B + 1)) | (g & ((1 << B) - 1));
        int r1 = r0 | (1 << B);
        float v0 = a[r0], v1 = a[r1];
        float o0 = c * v0 - s * v1;
        float o1 = s * v0 + c * v1;
        a[r0] = swap ? o1 : o0;
        a[r1] = swap ? o0 : o1;
    }
}
// Fused RY(tgt = reg bit BT) then CNOT(ctrl = reg bit BT+1, tgt = reg bit BT).
template <int BT>
__device__ __forceinline__ void quad_gate(float (&a)[64], float s, float c) {
#pragma unroll
    for (int g = 0; g < 16; ++g) {
        int lo  = g & ((1 << BT) - 1);
        int r00 = ((g >> BT) << (BT + 2)) | lo;
        int r01 = r00 | (1 << BT);
        int r10 = r00 | (2 << BT);
        int r11 = r00 | (3 << BT);
        float v00 = a[r00], v01 = a[r01], v10 = a[r10], v11 = a[r11];
        a[r00] = c * v00 - s * v01;
        a[r01] = s * v00 + c * v01;
        a[r10] = s * v10 + c * v11;   // ctrl=1 half: RY then swap (CNOT)
        a[r11] = c * v10 - s * v11;
    }
}

// ---------------- Pass 1 (std -> pi): qubits 0..8 (bits 15..23) ----------------
// R9-proven (~32 us). 512 thr x 64 regs, 64 KiB LDS, contiguous pi writes.
__global__ __launch_bounds__(512)
void pass1_pi_kernel(const float* __restrict__ src, float* __restrict__ dst,
                     const float* __restrict__ angles, int blk_b) {
    __shared__ float lds[16384];
    const int tid  = threadIdx.x;
    const int lane = tid & 63;
    const int w    = tid >> 6;
    const int blk  = blockIdx.x;                 // e6..14
    const float* ang = angles + blk_b * N_QUBITS;
    const size_t lowbase = ((size_t)blk << 6) | (size_t)lane;

    float a[64];
#pragma unroll
    for (int r = 0; r < 64; ++r)
        a[r] = src[((size_t)((r << 3) | w) << 15) | lowbase];

    float s, c;
    sincosf(0.5f * ang[0], &s, &c); pair_bit<5>(a, s, c, 0);
    sincosf(0.5f * ang[1], &s, &c); quad_gate<4>(a, s, c);
    sincosf(0.5f * ang[2], &s, &c); quad_gate<3>(a, s, c);
    sincosf(0.5f * ang[3], &s, &c); quad_gate<2>(a, s, c);
    sincosf(0.5f * ang[4], &s, &c); quad_gate<1>(a, s, c);
    sincosf(0.5f * ang[5], &s, &c); quad_gate<0>(a, s, c);

#pragma unroll
    for (int cb = 0; cb < 2; ++cb) {
        if (cb) __syncthreads();
#pragma unroll
        for (int rr = 0; rr < 32; ++rr)
            lds[(rr << 9) | (w << 6) | lane] = a[(cb << 5) | rr];
        __syncthreads();
#pragma unroll
        for (int q = 0; q < 32; ++q) {
            int h = (((q >> 1) & 1) << 13) | ((q & 1) << 12) | (w << 9)
                  | (((q >> 4) & 1) << 8) | (((q >> 3) & 1) << 7) | (((q >> 2) & 1) << 6)
                  | lane;
            a[(cb << 5) | q] = lds[h];
        }
    }

    sincosf(0.5f * ang[6], &s, &c); pair_bit<4>(a, s, c, w & 1);
    sincosf(0.5f * ang[7], &s, &c); quad_gate<3>(a, s, c);
    sincosf(0.5f * ang[8], &s, &c); quad_gate<2>(a, s, c);

    // store pi: H bit k = e(15+k) (identity ordering)
#pragma unroll
    for (int r = 0; r < 64; ++r) {
        int H = (((r >> 5) & 1) << 8) | (((r >> 1) & 1) << 7) | ((r & 1) << 6) | (w << 3)
              | (((r >> 4) & 1) << 2) | (((r >> 3) & 1) << 1) | ((r >> 2) & 1);
        dst[((size_t)blk << 15) | (H << 6) | lane] = a[r];
    }
}

// ---------------- Pass 2+3 tail: qubits 9..23 on a 32768-float chunk -----------
// L0 (entry): regs = (e9..13, e14@5), w = e6..8, lane = e0..5.
// T1 (chunk by e14, swizzle addr bit4 ^= e9):
//   L1: regs = (e4..8, e14@5), lane = (e0..3, e9@4, e10@5), w = e11..13.
// Gates: q9..14 reg (L0); q15..19 reg (L1, q15 ctrl e9 = lane4);
//        q20..23 lane shfl (masks 8,4,2,1; q20 ctrl e4 = reg bit0).
template <bool SQUARE>
__device__ __forceinline__ void p23_tail(float (&a)[64], float* __restrict__ lds,
                                         float* __restrict__ base, const float* ang,
                                         int lane, int w, int c15) {
    float s, c;
    // phase 1: qubits 9..14 on L0 regs
    sincosf(0.5f * ang[9], &s, &c);  pair_bit<5>(a, s, c, c15);   // q9: tgt e14, ctrl e15
    sincosf(0.5f * ang[10], &s, &c); quad_gate<4>(a, s, c);       // q10: tgt e13 ctrl e14
    sincosf(0.5f * ang[11], &s, &c); quad_gate<3>(a, s, c);
    sincosf(0.5f * ang[12], &s, &c); quad_gate<2>(a, s, c);
    sincosf(0.5f * ang[13], &s, &c); quad_gate<1>(a, s, c);
    sincosf(0.5f * ang[14], &s, &c); quad_gate<0>(a, s, c);       // q14: tgt e9 ctrl e10

    // T1: chunk by e14 (reg bit5 both sides), 16K floats/round.
    // write: addr = (lane ^ (e9<<4)) | w<<6 | j<<9                  (j = e9..13)
    // read:  h = (lane&15) | k<<4 | e9<<9 | e10<<10 | w<<11, addr = h ^ (e9<<4)
    //        -> addr bit4 = e4 ^ e9 on both sides: <=2-way banks, bijective.
#pragma unroll
    for (int x = 0; x < 2; ++x) {
        if (x) __syncthreads();
#pragma unroll
        for (int j = 0; j < 32; ++j)
            lds[(lane ^ ((j & 1) << 4)) | (w << 6) | (j << 9)] = a[(x << 5) | j];
        __syncthreads();
#pragma unroll
        for (int k = 0; k < 32; ++k) {
            int h = (lane & 15) | (k << 4) | (((lane >> 4) & 1) << 9)
                  | (((lane >> 5) & 1) << 10) | (w << 11);
            a[(x << 5) | k] = lds[h ^ ((((lane >> 4) & 1)) << 4)];
        }
    }

    // phase 2: qubits 15..19 on L1 regs (k0..k4 = e4..e8)
    sincosf(0.5f * ang[15], &s, &c); pair_bit<4>(a, s, c, (lane >> 4) & 1); // q15: tgt e8 ctrl e9
    sincosf(0.5f * ang[16], &s, &c); quad_gate<3>(a, s, c);                 // q16: tgt e7 ctrl e8
    sincosf(0.5f * ang[17], &s, &c); quad_gate<2>(a, s, c);
    sincosf(0.5f * ang[18], &s, &c); quad_gate<1>(a, s, c);
    sincosf(0.5f * ang[19], &s, &c); quad_gate<0>(a, s, c);                 // q19: tgt e4 ctrl e5

    // phase 3: q20..23 lane shfl gates. Butterfly: out = A*v + B*partner.
    //   gam=0: (A,B) = (c, tau? s : -s);  gam=1: (A,B) = (tau? -s : s, c)
    // q20: tgt e3 (mask 8), ctrl e4 = reg bit0 (per-reg)
    sincosf(0.5f * ang[20], &s, &c);
    {
        const int tau = (lane >> 3) & 1;
        const float A0 = c,            B0 = tau ? s : -s;   // gam = 0 (even regs)
        const float A1 = tau ? -s : s, B1 = c;              // gam = 1 (odd regs)
#pragma unroll
        for (int r = 0; r < 64; ++r) {
            float p = __shfl_xor(a[r], 8);
            float A = (r & 1) ? A1 : A0;
            float B = (r & 1) ? B1 : B0;
            a[r] = A * a[r] + B * p;
        }
    }
    // q21..23: tgt = lane bit bt (2..0), ctrl = lane bit bt+1
#pragma unroll
    for (int q = 21; q <= 23; ++q) {
        const int bt = 23 - q;                 // 2..0
        sincosf(0.5f * ang[q], &s, &c);
        const int tau = (lane >> bt) & 1;
        const int gam = (lane >> (bt + 1)) & 1;
        const float A = gam ? (tau ? -s : s) : c;
        const float B = gam ? c : (tau ? s : -s);
#pragma unroll
        for (int r = 0; r < 64; ++r) {
            float p = __shfl_xor(a[r], 1 << bt);
            a[r] = A * a[r] + B * p;
        }
    }

    if (SQUARE) {
#pragma unroll
        for (int r = 0; r < 64; ++r) a[r] *= a[r];
    }

    // store STANDARD from L1: local addr = e0..3 | e4..8(k) | e9,e10(lane) | e11..13(w) | e14(k5)
#pragma unroll
    for (int k = 0; k < 64; ++k)
        base[(lane & 15) | ((k & 31) << 4) | (((lane >> 4) & 1) << 9)
             | (((lane >> 5) & 1) << 10) | (w << 11) | (((k >> 5) & 1) << 14)] = a[k];
}

// P23: read pi from src, write standard to dst. H is identity-ordered, so
// chunk<<15 IS the standard high-bit base (the R10 bug fix).
template <bool SQUARE>
__global__ __launch_bounds__(512)
void pass23_pi_kernel(const float* __restrict__ src, float* __restrict__ dst,
                      const float* __restrict__ angles, int blk_b) {
    __shared__ float lds[16384];
    const int tid  = threadIdx.x;
    const int lane = tid & 63;
    const int w    = tid >> 6;
    const int chunk = blockIdx.x;                // = H, H_k = e(15+k)
    float* __restrict__ base = dst + ((size_t)chunk << 15);
    const int c15 = chunk & 1;                   // e15
    const float* ang = angles + blk_b * N_QUBITS;

    float a[64];
    // read pi: addr = (e6..14 = r<<3|w)<<15 | chunk<<6 | lane  (L0 entry layout)
#pragma unroll
    for (int r = 0; r < 64; ++r)
        a[r] = src[((size_t)((r << 3) | w) << 15) | ((size_t)chunk << 6) | (size_t)lane];

    p23_tail<SQUARE>(a, lds, base, ang, lane, w, c15);
}

// Block 0 fused: after qubits 0..8 from |0..0>, state = f9[e15..23] * delta(e0..14).
// f9 index bit k = e(15+k) = chunk bit k -> amp = f[chunk].
__global__ __launch_bounds__(512)
void pass23_init_kernel(float* __restrict__ dst, const float* __restrict__ angles) {
    __shared__ float lds[16384];
    const int tid  = threadIdx.x;
    const int lane = tid & 63;
    const int w    = tid >> 6;
    const int chunk = blockIdx.x;
    float* __restrict__ base = dst + ((size_t)chunk << 15);
    const float* ang = angles;                   // block 0
    float s, c;

    float* f = lds;
    f[tid] = 0.0f;
    __syncthreads();
    if (tid == 0) f[0] = 1.0f;
    __syncthreads();
    sincosf(0.5f * ang[0], &s, &c);
    if (tid < 256) {
        float v0 = f[tid], v1 = f[tid | 256];
        f[tid]       = c * v0 - s * v1;
        f[tid | 256] = s * v0 + c * v1;
    }
    __syncthreads();
    for (int q = 1; q <= 8; ++q) {
        sincosf(0.5f * ang[q], &s, &c);
        int bt = 8 - q;
        if (tid < 128) {
            int lo  = tid & ((1 << bt) - 1);
            int r00 = ((tid >> bt) << (bt + 2)) | lo;
            int r01 = r00 | (1 << bt);
            int r10 = r00 | (2 << bt);
            int r11 = r00 | (3 << bt);
            float v00 = f[r00], v01 = f[r01], v10 = f[r10], v11 = f[r11];
            f[r00] = c * v00 - s * v01;
            f[r01] = s * v00 + c * v01;
            f[r10] = s * v10 + c * v11;
            f[r11] = c * v10 - s * v11;
        }
        __syncthreads();
    }
    const float amp = f[chunk];
    __syncthreads();                             // lds reused by the tail

    float a[64];
#pragma unroll
    for (int r = 0; r < 64; ++r) a[r] = 0.0f;
    if (tid == 0) a[0] = amp;                    // element (e0..14)=0 -> r=0, w=0, lane=0

    p23_tail<false>(a, lds, base, ang, lane, w, chunk & 1);
}

extern "C" void kernel_launch(void* const* d_in, const int* in_sizes, int n_in,
                              void* d_out, int out_size, void* d_ws, size_t ws_size,
                              hipStream_t stream) {
    const float* angles = (const float*)d_in[0];
    float* out = (float*)d_out;
    float* ws  = (float*)d_ws;

    pass23_init_kernel<<<NSTATE >> 15, 512, 0, stream>>>(out, angles);

    for (int b = 1; b < N_BLOCKS; ++b) {
        const bool last = (b == N_BLOCKS - 1);
        pass1_pi_kernel<<<NSTATE >> 15, 512, 0, stream>>>(out, ws, angles, b);
        if (last)
            pass23_pi_kernel<true><<<NSTATE >> 15, 512, 0, stream>>>(ws, out, angles, b);
        else
            pass23_pi_kernel<false><<<NSTATE >> 15, 512, 0, stream>>>(ws, out, angles, b);
    }
}